// Round 1
// baseline (1140.091 us; speedup 1.0000x reference)
//
#include <hip/hip_runtime.h>
#include <math.h>

// Problem constants (MixtureLowRankRNN)
#define HIDDEN_ 1024
#define RANK_ 4
#define INPUT_ 16
#define T_ 1024
#define BATCH_ 32

#define NTHREADS_ 512
#define EPT_ (HIDDEN_ / NTHREADS_)   // 2 h-elements per thread
#define NWAVES_ (NTHREADS_ / 64)     // 8 waves

__device__ __forceinline__ float exp2_fast(float x) {
#if defined(__has_builtin)
#if __has_builtin(__builtin_amdgcn_exp2f)
    return __builtin_amdgcn_exp2f(x);
#else
    return exp2f(x);
#endif
#else
    return exp2f(x);
#endif
}

// tanh(x) = 1 - 2/(exp(2x)+1); exp(2x) = 2^(2*log2(e)*x)
// abs error ~2e-7 everywhere; handles +-inf overflow correctly (-> +-1).
__device__ __forceinline__ float tanh_fast(float x) {
    float e = exp2_fast(x * 2.885390081777926815f); // 2*log2(e)
    return 1.0f - 2.0f / (e + 1.0f);
}

// One block per batch element. h kept entirely in registers (2 elems/thread).
// Output identity: pinv([m|I]) @ [m|I] = I_20, so
//   y_t = 0.9*y_{t-1} + [0.1*scale*s_t ; 0.1*x_t]
// with s_t = n^T tanh(h_{t-1}).  No pinv / projection GEMM needed.
__global__ __launch_bounds__(NTHREADS_) void rnn_scan_kernel(
    const float* __restrict__ x,     // [B, T, 16]
    const float* __restrict__ m,     // [H, 4]
    const float* __restrict__ n,     // [H, 4]
    const float* __restrict__ imat,  // [H, 16]
    float* __restrict__ out)         // [B, T, 20]
{
    const int b    = blockIdx.x;
    const int tid  = threadIdx.x;
    const int wave = tid >> 6;
    const int lane = tid & 63;

    float h[EPT_];
    float mr[EPT_][RANK_];
    float nr[EPT_][RANK_];
    float Ir[EPT_][INPUT_];

#pragma unroll
    for (int j = 0; j < EPT_; ++j) {
        const int hidx = tid * EPT_ + j;
        h[j] = 0.0f;
        const float4 mv = *(const float4*)(m + hidx * RANK_);
        mr[j][0] = mv.x; mr[j][1] = mv.y; mr[j][2] = mv.z; mr[j][3] = mv.w;
        const float4 nv = *(const float4*)(n + hidx * RANK_);
        nr[j][0] = nv.x; nr[j][1] = nv.y; nr[j][2] = nv.z; nr[j][3] = nv.w;
#pragma unroll
        for (int q = 0; q < 4; ++q) {
            const float4 iv = *(const float4*)(imat + hidx * INPUT_ + q * 4);
            Ir[j][q*4+0] = iv.x; Ir[j][q*4+1] = iv.y;
            Ir[j][q*4+2] = iv.z; Ir[j][q*4+3] = iv.w;
        }
    }

    // parity double-buffer -> single __syncthreads per step
    __shared__ float4 part[2][NWAVES_];

    const float* xb = x + (size_t)b * T_ * INPUT_;
    float* ob = out + (size_t)b * T_ * (RANK_ + INPUT_);

    const float kd   = 0.9f;                      // 1 - ALPHA
    const float krec = 0.1f * (500.0f / 1024.0f); // ALPHA * BASE_SCALE / HIDDEN
    const float kin  = 0.1f;                      // ALPHA

    float y = 0.0f;  // output accumulator (used by tid < 20)

    for (int t = 0; t < T_; ++t) {
        const float* xt = xb + t * INPUT_;
        float xr[INPUT_];
#pragma unroll
        for (int q = 0; q < 4; ++q) {
            float4 v = ((const float4*)xt)[q];   // wave-uniform address, L1 broadcast
            xr[q*4+0] = v.x; xr[q*4+1] = v.y; xr[q*4+2] = v.z; xr[q*4+3] = v.w;
        }

        // s partials: n^T tanh(h)
        float p0 = 0.f, p1 = 0.f, p2 = 0.f, p3 = 0.f;
#pragma unroll
        for (int j = 0; j < EPT_; ++j) {
            float th = tanh_fast(h[j]);
            p0 = fmaf(th, nr[j][0], p0);
            p1 = fmaf(th, nr[j][1], p1);
            p2 = fmaf(th, nr[j][2], p2);
            p3 = fmaf(th, nr[j][3], p3);
        }
        // butterfly reduce across the 64-lane wave
#pragma unroll
        for (int d = 32; d >= 1; d >>= 1) {
            p0 += __shfl_xor(p0, d);
            p1 += __shfl_xor(p1, d);
            p2 += __shfl_xor(p2, d);
            p3 += __shfl_xor(p3, d);
        }
        if (lane == 0) part[t & 1][wave] = make_float4(p0, p1, p2, p3);
        __syncthreads();
        float s0 = 0.f, s1 = 0.f, s2 = 0.f, s3 = 0.f;
#pragma unroll
        for (int w = 0; w < NWAVES_; ++w) {
            float4 q = part[t & 1][w];   // broadcast read, conflict-free
            s0 += q.x; s1 += q.y; s2 += q.z; s3 += q.w;
        }

        // h <- 0.9 h + krec*(m@s) + 0.1*(I@x_t)
#pragma unroll
        for (int j = 0; j < EPT_; ++j) {
            float acc = xr[0] * Ir[j][0];
#pragma unroll
            for (int i = 1; i < INPUT_; ++i)
                acc = fmaf(xr[i], Ir[j][i], acc);
            float rec = s0 * mr[j][0];
            rec = fmaf(s1, mr[j][1], rec);
            rec = fmaf(s2, mr[j][2], rec);
            rec = fmaf(s3, mr[j][3], rec);
            h[j] = fmaf(kd, h[j], fmaf(krec, rec, kin * acc));
        }

        // y_t = 0.9 y_{t-1} + [krec*s ; kin*x_t]  (lanes 0..19 of wave 0)
        if (tid < 20) {
            float drive;
            if (tid < 4) {
                float sv = (tid == 0) ? s0 : (tid == 1) ? s1 : (tid == 2) ? s2 : s3;
                drive = krec * sv;
            } else {
                drive = kin * xt[tid - 4];
            }
            y = fmaf(kd, y, drive);
            ob[t * 20 + tid] = y;
        }
    }
}

extern "C" void kernel_launch(void* const* d_in, const int* in_sizes, int n_in,
                              void* d_out, int out_size, void* d_ws, size_t ws_size,
                              hipStream_t stream) {
    const float* x    = (const float*)d_in[0];
    const float* m    = (const float*)d_in[1];
    const float* n    = (const float*)d_in[2];
    const float* imat = (const float*)d_in[3];
    float* out = (float*)d_out;

    rnn_scan_kernel<<<dim3(BATCH_), dim3(NTHREADS_), 0, stream>>>(x, m, n, imat, out);
}

// Round 2
// 604.097 us; speedup vs baseline: 1.8873x; 1.8873x over previous
//
#include <hip/hip_runtime.h>
#include <math.h>

// Problem constants (MixtureLowRankRNN)
#define HIDDEN_ 1024
#define RANK_ 4
#define INPUT_ 16
#define T_ 1024
#define BATCH_ 32

#define NTHREADS_ 256
#define NWAVES_ (NTHREADS_ / 64)     // 4 waves, one per SIMD
#define EPT_ (HIDDEN_ / NTHREADS_)   // 4 h-elements per thread

__device__ __forceinline__ float fast_exp2(float x) {
#if defined(__has_builtin)
#if __has_builtin(__builtin_amdgcn_exp2f)
    return __builtin_amdgcn_exp2f(x);
#else
    return exp2f(x);
#endif
#else
    return exp2f(x);
#endif
}

__device__ __forceinline__ float fast_rcp(float x) {
#if defined(__has_builtin)
#if __has_builtin(__builtin_amdgcn_rcpf)
    return __builtin_amdgcn_rcpf(x);
#else
    return 1.0f / x;
#endif
#else
    return 1.0f / x;
#endif
}

// tanh(x) = 1 - 2/(exp(2x)+1); exp(2x) = 2^(2*log2(e)*x).
// v_exp_f32 + v_rcp_f32: ~1 ulp each, abs err ~1e-6. Handles overflow (-> +-1).
__device__ __forceinline__ float tanh_fast(float x) {
    float e = fast_exp2(x * 2.885390081777926815f); // 2*log2(e)
    return fmaf(-2.0f, fast_rcp(e + 1.0f), 1.0f);
}

// One DPP reduce step: v += dpp_mov(v, ctrl) with old=0, bound_ctrl=1
// (OOB/masked-off reads contribute 0). VALU latency, not LDS pipe.
#define DPP_ADD(v, ctrl)                                                          \
    do {                                                                          \
        int _t = __builtin_amdgcn_update_dpp(0, __float_as_int(v), (ctrl), 0xf,   \
                                             0xf, true);                          \
        (v) += __int_as_float(_t);                                                \
    } while (0)

// Full wave64 sum; result valid in lane 63.
// row_shr:1,2,4,8 -> lane 15/31/47/63 hold their 16-lane row sums;
// row_bcast15 -> lane31 = rows0+1, lane63 = rows2+3; row_bcast31 -> lane63 = all.
#define WAVE_RED_TO_LANE63(v)  \
    DPP_ADD(v, 0x111);         \
    DPP_ADD(v, 0x112);         \
    DPP_ADD(v, 0x114);         \
    DPP_ADD(v, 0x118);         \
    DPP_ADD(v, 0x142);         \
    DPP_ADD(v, 0x143)

// One block per batch element; h entirely in registers (4 elems/thread).
// Output identity: pinv([m|I]) @ [m|I] = I_20, so
//   y_t = 0.9*y_{t-1} + [krec*s_t ; kin*x_t],  s_t = n^T tanh(h_{t-1}).
__global__ __launch_bounds__(NTHREADS_) void rnn_scan_kernel(
    const float* __restrict__ x,     // [B, T, 16]
    const float* __restrict__ m,     // [H, 4]
    const float* __restrict__ n,     // [H, 4]
    const float* __restrict__ imat,  // [H, 16]
    float* __restrict__ out)         // [B, T, 20]
{
    const int b    = blockIdx.x;
    const int tid  = threadIdx.x;
    const int wave = tid >> 6;
    const int lane = tid & 63;

    const float kd   = 0.9f;                      // 1 - ALPHA
    const float krec = 0.1f * (500.0f / 1024.0f); // ALPHA * BASE_SCALE / HIDDEN
    const float kin  = 0.1f;                      // ALPHA

    float h[EPT_];
    float mrs[EPT_][RANK_];    // krec * m row
    float nr[EPT_][RANK_];
    float Irs[EPT_][INPUT_];   // kin * I row

#pragma unroll
    for (int j = 0; j < EPT_; ++j) {
        const int hidx = tid * EPT_ + j;
        h[j] = 0.0f;
        const float4 mv = *(const float4*)(m + hidx * RANK_);
        mrs[j][0] = krec * mv.x; mrs[j][1] = krec * mv.y;
        mrs[j][2] = krec * mv.z; mrs[j][3] = krec * mv.w;
        const float4 nv = *(const float4*)(n + hidx * RANK_);
        nr[j][0] = nv.x; nr[j][1] = nv.y; nr[j][2] = nv.z; nr[j][3] = nv.w;
#pragma unroll
        for (int q = 0; q < 4; ++q) {
            const float4 iv = *(const float4*)(imat + hidx * INPUT_ + q * 4);
            Irs[j][q*4+0] = kin * iv.x; Irs[j][q*4+1] = kin * iv.y;
            Irs[j][q*4+2] = kin * iv.z; Irs[j][q*4+3] = kin * iv.w;
        }
    }

    // parity double-buffer -> single __syncthreads per step
    __shared__ float4 part[2][NWAVES_];

    const float* xb = x + (size_t)b * T_ * INPUT_;
    float* ob = out + (size_t)b * T_ * (RANK_ + INPUT_);

    float y = 0.0f;  // output accumulator (tid < 20)
    // y-drive scalar for lanes 4..19: prefetched one step ahead to hide latency
    const bool is_xy = (tid >= 4 && tid < 20);
    float xy = is_xy ? xb[tid - 4] : 0.0f;

    for (int t = 0; t < T_; ++t) {
        // --- issue all global loads for this step first ---
        const float* xt = xb + t * INPUT_;
        float xr[INPUT_];
#pragma unroll
        for (int q = 0; q < 4; ++q) {
            float4 v = ((const float4*)xt)[q];   // wave-uniform, L1 broadcast
            xr[q*4+0] = v.x; xr[q*4+1] = v.y; xr[q*4+2] = v.z; xr[q*4+3] = v.w;
        }
        float xy_nxt = 0.0f;
        if (is_xy) {
            int tn = (t + 1 < T_) ? (t + 1) : t;     // clamp; value unused at t=T-1
            xy_nxt = xb[tn * INPUT_ + (tid - 4)];
        }

        // --- s partials: n^T tanh(h) over this thread's 4 elements ---
        float th[EPT_];
#pragma unroll
        for (int j = 0; j < EPT_; ++j) th[j] = tanh_fast(h[j]);

        float p0 = th[0] * nr[0][0], p1 = th[0] * nr[0][1];
        float p2 = th[0] * nr[0][2], p3 = th[0] * nr[0][3];
#pragma unroll
        for (int j = 1; j < EPT_; ++j) {
            p0 = fmaf(th[j], nr[j][0], p0);
            p1 = fmaf(th[j], nr[j][1], p1);
            p2 = fmaf(th[j], nr[j][2], p2);
            p3 = fmaf(th[j], nr[j][3], p3);
        }

        // --- wave reduce via DPP (VALU), level-major for ILP across 4 ranks ---
        DPP_ADD(p0, 0x111); DPP_ADD(p1, 0x111); DPP_ADD(p2, 0x111); DPP_ADD(p3, 0x111);
        DPP_ADD(p0, 0x112); DPP_ADD(p1, 0x112); DPP_ADD(p2, 0x112); DPP_ADD(p3, 0x112);
        DPP_ADD(p0, 0x114); DPP_ADD(p1, 0x114); DPP_ADD(p2, 0x114); DPP_ADD(p3, 0x114);
        DPP_ADD(p0, 0x118); DPP_ADD(p1, 0x118); DPP_ADD(p2, 0x118); DPP_ADD(p3, 0x118);
        DPP_ADD(p0, 0x142); DPP_ADD(p1, 0x142); DPP_ADD(p2, 0x142); DPP_ADD(p3, 0x142);
        DPP_ADD(p0, 0x143); DPP_ADD(p1, 0x143); DPP_ADD(p2, 0x143); DPP_ADD(p3, 0x143);

        if (lane == 63) part[t & 1][wave] = make_float4(p0, p1, p2, p3);
        __syncthreads();

        const float4 q0 = part[t & 1][0];
        const float4 q1 = part[t & 1][1];
        const float4 q2 = part[t & 1][2];
        const float4 q3 = part[t & 1][3];
        const float s0 = (q0.x + q1.x) + (q2.x + q3.x);
        const float s1 = (q0.y + q1.y) + (q2.y + q3.y);
        const float s2 = (q0.z + q1.z) + (q2.z + q3.z);
        const float s3 = (q0.w + q1.w) + (q2.w + q3.w);

        // --- h <- kd*h + (krec*m)@s + (kin*I)@x_t ---
#pragma unroll
        for (int j = 0; j < EPT_; ++j) {
            float a = xr[0] * Irs[j][0];
#pragma unroll
            for (int i = 1; i < INPUT_; ++i)
                a = fmaf(xr[i], Irs[j][i], a);
            a = fmaf(s0, mrs[j][0], a);
            a = fmaf(s1, mrs[j][1], a);
            a = fmaf(s2, mrs[j][2], a);
            a = fmaf(s3, mrs[j][3], a);
            h[j] = fmaf(kd, h[j], a);
        }

        // --- y_t = kd*y_{t-1} + [krec*s ; kin*x_t]  (lanes 0..19 of wave 0) ---
        if (tid < 20) {
            float drive;
            if (tid < 4) {
                float sv = (tid == 0) ? s0 : (tid == 1) ? s1 : (tid == 2) ? s2 : s3;
                drive = krec * sv;
            } else {
                drive = kin * xy;
            }
            y = fmaf(kd, y, drive);
            ob[t * 20 + tid] = y;
        }
        xy = xy_nxt;
    }
}

extern "C" void kernel_launch(void* const* d_in, const int* in_sizes, int n_in,
                              void* d_out, int out_size, void* d_ws, size_t ws_size,
                              hipStream_t stream) {
    const float* x    = (const float*)d_in[0];
    const float* m    = (const float*)d_in[1];
    const float* n    = (const float*)d_in[2];
    const float* imat = (const float*)d_in[3];
    float* out = (float*)d_out;

    rnn_scan_kernel<<<dim3(BATCH_), dim3(NTHREADS_), 0, stream>>>(x, m, n, imat, out);
}